// Round 7
// baseline (287.109 us; speedup 1.0000x reference)
//
#include <hip/hip_runtime.h>
#include <stdint.h>

// ---------------- types ----------------
typedef _Float16 f16x8 __attribute__((ext_vector_type(8)));
typedef __fp16   fp16x2 __attribute__((ext_vector_type(2)));
typedef float    f32x16 __attribute__((ext_vector_type(16)));

union Frag {
  f16x8    v;
  uint32_t w[4];
  _Float16 h[8];
};

union CVec {
  float4 q[4];
  f32x16 v;
};

__device__ __forceinline__ uint32_t pack2h(float a, float b) {
  union { _Float16 h[2]; uint32_t u; } r;
  r.h[0] = (_Float16)a;   // RNE f32->f16
  r.h[1] = (_Float16)b;
  return r.u;
}

__device__ __forceinline__ uint32_t pkrtz(float a, float b) {
  union { fp16x2 h2; uint32_t u; } cv;
  cv.h2 = __builtin_amdgcn_cvt_pkrtz(a, b);
  return cv.u;
}

__device__ __forceinline__ void g2lds16(const void* g, void* l) {
  __builtin_amdgcn_global_load_lds(
      (const __attribute__((address_space(1))) uint32_t*)g,
      (__attribute__((address_space(3))) uint32_t*)l, 16, 0, 0);
}

// ---------------- prep: fragment-order the weights (f16) ----------------
// ws layout (bytes):
//   wfrag   @ 0      : [9][4 ot][8 kt][64 lane][8 j] f16  = 294912 B
//   w0frag  @ 294912 : [4 ot][64 lane][8 j]          f16  = 4096 B   (K padded 4->16)
//   biasC   @ 299008 : [10 l][4 ot][2 h][16 r]       f32  = 5120 B   (MFMA C-operand order)
//   woutf16 @ 304128 : [8 kt][64 lane][8 j]          f16  = 8192 B   (A-frag, rows!=0 zeroed)
// fragment value convention (32x32x16 f16 MFMA):
//   A lane l holds row i = l&31, k = (l>>5)*8 + j
//   B lane l holds col j = l&31, k = (l>>5)*8 + j
//   D/C lane l holds col = l&31, row = (r&3) + 8*(r>>2) + 4*(l>>5)
__global__ void prep_kernel(const float* __restrict__ W0, const float* __restrict__ b0,
                            const float* __restrict__ Wh, const float* __restrict__ bh,
                            const float* __restrict__ Wout,
                            _Float16* __restrict__ wfrag, _Float16* __restrict__ w0frag,
                            float* __restrict__ biasC, _Float16* __restrict__ woutf16) {
  const int stride = gridDim.x * blockDim.x;
  for (int idx = blockIdx.x * blockDim.x + threadIdx.x; idx < 154880; idx += stride) {
    if (idx < 147456) {                       // wfrag: Wh[l][o][k] -> A-fragment order
      const int j = idx & 7, lane = (idx >> 3) & 63, kt = (idx >> 9) & 7,
                ot = (idx >> 12) & 3, l = idx >> 14;
      const int o = ot * 32 + (lane & 31);
      const int k = kt * 16 + (lane >> 5) * 8 + j;
      wfrag[idx] = (_Float16)Wh[(l * 128 + o) * 128 + k];
    } else if (idx < 147456 + 2048) {         // w0frag (K padded with zeros)
      const int i = idx - 147456;
      const int j = i & 7, lane = (i >> 3) & 63, ot = i >> 9;
      const int o = ot * 32 + (lane & 31);
      const int k = (lane >> 5) * 8 + j;
      w0frag[i] = (_Float16)(k < 4 ? W0[o * 4 + k] : 0.0f);
    } else if (idx < 147456 + 2048 + 1280) {  // biasC: C-operand order per (l,ot,h)
      const int i = idx - (147456 + 2048);
      const int r = i & 15, hh = (i >> 4) & 1, ot = (i >> 5) & 3, l = i >> 7;
      const int row = (r & 3) + 8 * (r >> 2) + 4 * hh;
      const int o = ot * 32 + row;
      biasC[i] = (l == 0) ? b0[o] : bh[(l - 1) * 128 + o];
    } else {                                  // Wout as masked A-fragment (row 0 only), f16
      const int i = idx - (147456 + 2048 + 1280);
      const int j = i & 7, lane = (i >> 3) & 63, kt = i >> 9;
      const int k = kt * 16 + (lane >> 5) * 8 + j;
      woutf16[i] = ((lane & 31) == 0) ? (_Float16)Wout[k] : (_Float16)0.0f;
    }
  }
}

// ---------------- fused MLP ----------------
__global__ __launch_bounds__(256, 2) void mlp_fused(
    const float* __restrict__ x,
    const _Float16* __restrict__ wfrag,
    const _Float16* __restrict__ w0frag,
    const float* __restrict__ biasCg,
    const _Float16* __restrict__ woutf16,
    const float* __restrict__ boutp,
    float* __restrict__ out) {
  // 2 x 32 KB W double-buffer + bias C-table; 70.7 KB -> 2 blocks/CU
  __shared__ __align__(16) unsigned char ldsW[2][32768];
  __shared__ __align__(16) float ldsBiasC[1280];

  const int t    = threadIdx.x;
  const int lane = t & 63;
  const int wv   = t >> 6;
  const int h    = lane >> 5;   // half-wave
  const int ln   = lane & 31;
  const long rowbase = (long)blockIdx.x * 256 + wv * 64;  // + nt*32 + ln

  // ---- prologue staging: W[1] -> ldsW[0]; bias C-table ----
  {
    const unsigned char* src = (const unsigned char*)wfrag;  // layer 1 at offset 0
#pragma unroll
    for (int i = 0; i < 8; ++i) {
      const int off = i * 4096 + t * 16;
      g2lds16(src + off, &ldsW[0][off]);
    }
    const unsigned char* bsrc = (const unsigned char*)biasCg;
    g2lds16(bsrc + t * 16, (unsigned char*)ldsBiasC + t * 16);            // chunks 0..255
    if (t < 64) g2lds16(bsrc + (256 + t) * 16, (unsigned char*)ldsBiasC + (256 + t) * 16);
  }

  Frag   B[2][8];      // current-layer input fragments (H^T), per nt / k-tile
  f32x16 acc[4][2];    // [o-tile][n-tile], D = H_out^T
  const f32x16 fzero = (f32x16)0.0f;

  // broadcast read of the per-(layer,ot,half) C-operand (bias pre-placed in D order)
  auto load_cvec = [&](int l, int ot) -> f32x16 {
    CVec cv;
    const float* p = ldsBiasC + ((l * 4 + ot) * 2 + h) * 16;
#pragma unroll
    for (int g = 0; g < 4; ++g) cv.q[g] = *(const float4*)(p + g * 4);
    return cv.v;
  };

  // E-chunk: relu+pack acc[ot][nt] (bias already inside), permlane32 half-exchange,
  // writes B[nt][2ot] and B[nt][2ot+1]. Register-only; all indices compile-time.
  auto e_chunk = [&](int ot, int nt) {
    uint32_t P[4][2];
#pragma unroll
    for (int g = 0; g < 4; ++g) {
#pragma unroll
      for (int c = 0; c < 2; ++c) {
        const uint32_t cv = pkrtz(acc[ot][nt][g * 4 + c * 2 + 0],
                                  acc[ot][nt][g * 4 + c * 2 + 1]);
        uint32_t r;
        asm("v_pk_max_f16 %0, %1, %2" : "=v"(r) : "v"(cv), "v"(0u));
        P[g][c] = r;
      }
    }
#pragma unroll
    for (int u = 0; u < 2; ++u) {
      uint32_t a0 = P[2 * u][0], b0v = P[2 * u + 1][0];
      uint32_t a1 = P[2 * u][1], b1v = P[2 * u + 1][1];
      asm("v_permlane32_swap_b32 %0, %1" : "+v"(a0), "+v"(b0v));
      asm("v_permlane32_swap_b32 %0, %1" : "+v"(a1), "+v"(b1v));
      Frag nb;
      nb.w[0] = a0;   // h==0: own lo pair | h==1: partner's lo pair
      nb.w[1] = a1;
      nb.w[2] = b0v;  // h==0: partner's hi pair | h==1: own hi pair
      nb.w[3] = b1v;
      B[nt][ot * 2 + u] = nb;
    }
  };

  // one nt-pass of a hidden layer: 32 MFMAs on acc[*][nt] consuming B[nt][*],
  // with the OTHER nt's epilogue chunks interleaved after odd kt steps.
  // E-chunks read acc[*][nt^1] (not written here) and write B[nt^1][*] (dead here).
  auto m_pass = [&](const unsigned char* wl, int l, int nt) {
#pragma unroll
    for (int kt = 0; kt < 8; ++kt) {
      f16x8 a[4];
#pragma unroll
      for (int ot = 0; ot < 4; ++ot)
        a[ot] = *(const f16x8*)(wl + ot * 8192 + kt * 1024 + lane * 16);
      if (kt == 0) {
#pragma unroll
        for (int ot = 0; ot < 4; ++ot) {
          const f32x16 cvec = load_cvec(l, ot);
          acc[ot][nt] = __builtin_amdgcn_mfma_f32_32x32x16_f16(a[ot], B[nt][0].v, cvec, 0, 0, 0);
        }
      } else {
#pragma unroll
        for (int ot = 0; ot < 4; ++ot)
          acc[ot][nt] = __builtin_amdgcn_mfma_f32_32x32x16_f16(a[ot], B[nt][kt].v, acc[ot][nt], 0, 0, 0);
      }
      if (kt & 1) e_chunk(kt >> 1, nt ^ 1);  // hide epilogue VALU under matrix drain
    }
  };

  // x loads + pack overlap the staging latency
  Frag xb[2];
#pragma unroll
  for (int nt = 0; nt < 2; ++nt) {
    float4 xv = make_float4(0.f, 0.f, 0.f, 0.f);
    if (h == 0) xv = *(const float4*)(x + (rowbase + nt * 32 + ln) * 4);
    xb[nt].w[0] = pack2h(xv.x, xv.y);
    xb[nt].w[1] = pack2h(xv.z, xv.w);
    xb[nt].w[2] = 0u;
    xb[nt].w[3] = 0u;
  }

  __syncthreads();  // staging drained (implicit vmcnt(0) lgkmcnt(0) before barrier)

  // ---- layer 0: K=16 zero-padded MFMA, C = bias (both nt; no LDS W) ----
#pragma unroll
  for (int ot = 0; ot < 4; ++ot) {
    const f16x8 a0 = *(const f16x8*)(w0frag + ot * 512 + lane * 8);
    const f32x16 cvec = load_cvec(0, ot);
    acc[ot][0] = __builtin_amdgcn_mfma_f32_32x32x16_f16(a0, xb[0].v, cvec, 0, 0, 0);
    acc[ot][1] = __builtin_amdgcn_mfma_f32_32x32x16_f16(a0, xb[1].v, cvec, 0, 0, 0);
  }
  // E0(1): produce B[0] for layer 1 (serial; pipeline fill)
#pragma unroll
  for (int c = 0; c < 4; ++c) e_chunk(c, 0);

  // ---- 9 hidden layers, nt-split software pipeline ----
  // R(l): pass0 = M(nt=0) ⊗ E(nt=1,layer l) ; pass1 = M(nt=1) ⊗ E(nt=0,layer l+1)
#pragma unroll
  for (int l = 1; l <= 9; ++l) {
    if (l < 9) {  // prefetch W[l+1] into buf[l&1]; drained by the layer-end barrier
      const unsigned char* src = (const unsigned char*)wfrag + (size_t)l * 32768;
#pragma unroll
      for (int i = 0; i < 8; ++i) {
        const int off = i * 4096 + t * 16;
        g2lds16(src + off, &ldsW[l & 1][off]);
      }
    }
    const unsigned char* wl = &ldsW[(l - 1) & 1][0];
    __builtin_amdgcn_s_setprio(1);
    m_pass(wl, l, 0);   // writes acc[*][0]; E-chunks build B[1] from old acc[*][1]
    m_pass(wl, l, 1);   // writes acc[*][1]; E-chunks build B[0] from new acc[*][0]
    __builtin_amdgcn_s_setprio(0);
    if (l < 9) __syncthreads();  // gates buf reuse; drains prefetch W[l+1]
  }

  // ---- output layer ----
  // B[0] was produced by the E-chunks inside pass1 of layer 9; finish B[1] here.
  {
    Frag wa[8];
#pragma unroll
    for (int kt = 0; kt < 8; ++kt)
      wa[kt].v = *(const f16x8*)(woutf16 + kt * 512 + lane * 8);
    const float boutv = *boutp;

#pragma unroll
    for (int c = 0; c < 4; ++c) e_chunk(c, 1);  // B[1] from acc[*][1] of layer 9

    f32x16 accO0 = fzero, accO1 = fzero;
#pragma unroll
    for (int kt = 0; kt < 8; ++kt) {
      accO0 = __builtin_amdgcn_mfma_f32_32x32x16_f16(wa[kt].v, B[0][kt].v, accO0, 0, 0, 0);
      accO1 = __builtin_amdgcn_mfma_f32_32x32x16_f16(wa[kt].v, B[1][kt].v, accO1, 0, 0, 0);
    }
    if (h == 0) {
      out[rowbase + ln]      = accO0[0] + boutv;
      out[rowbase + 32 + ln] = accO1[0] + boutv;
    }
  }
}

extern "C" void kernel_launch(void* const* d_in, const int* in_sizes, int n_in,
                              void* d_out, int out_size, void* d_ws, size_t ws_size,
                              hipStream_t stream) {
  (void)n_in; (void)out_size; (void)ws_size;  // needs ~313 KB of ws
  const float* x    = (const float*)d_in[0];
  const float* W0   = (const float*)d_in[1];
  const float* b0   = (const float*)d_in[2];
  const float* Wh   = (const float*)d_in[3];
  const float* bh   = (const float*)d_in[4];
  const float* Wout = (const float*)d_in[5];
  const float* bout = (const float*)d_in[6];
  float* out = (float*)d_out;

  char* ws = (char*)d_ws;
  _Float16* wfrag   = (_Float16*)(ws);
  _Float16* w0frag  = (_Float16*)(ws + 294912);
  float*    biasC   = (float*)(ws + 299008);
  _Float16* woutf16 = (_Float16*)(ws + 304128);

  const int n = in_sizes[0] / 4;  // 1048576 points

  prep_kernel<<<dim3(160), dim3(256), 0, stream>>>(W0, b0, Wh, bh, Wout,
                                                   wfrag, w0frag, biasC, woutf16);
  mlp_fused<<<dim3(n / 256), dim3(256), 0, stream>>>(x, wfrag, w0frag, biasC,
                                                     woutf16, bout, out);
}

// Round 8
// 269.259 us; speedup vs baseline: 1.0663x; 1.0663x over previous
//
#include <hip/hip_runtime.h>
#include <stdint.h>

// ---------------- types ----------------
typedef _Float16 f16x8 __attribute__((ext_vector_type(8)));
typedef __fp16   fp16x2 __attribute__((ext_vector_type(2)));
typedef float    f32x16 __attribute__((ext_vector_type(16)));

union Frag {
  f16x8    v;
  uint32_t w[4];
  _Float16 h[8];
};

union CVec {
  float4 q[4];
  f32x16 v;
};

__device__ __forceinline__ uint32_t pack2h(float a, float b) {
  union { _Float16 h[2]; uint32_t u; } r;
  r.h[0] = (_Float16)a;   // RNE f32->f16
  r.h[1] = (_Float16)b;
  return r.u;
}

__device__ __forceinline__ uint32_t pkrtz(float a, float b) {
  union { fp16x2 h2; uint32_t u; } cv;
  cv.h2 = __builtin_amdgcn_cvt_pkrtz(a, b);
  return cv.u;
}

__device__ __forceinline__ void g2lds16(const void* g, void* l) {
  __builtin_amdgcn_global_load_lds(
      (const __attribute__((address_space(1))) uint32_t*)g,
      (__attribute__((address_space(3))) uint32_t*)l, 16, 0, 0);
}

// ---------------- prep: fragment-order the weights (f16) ----------------
// ws layout (bytes):
//   wfrag   @ 0      : [9][4 ot][8 kt][64 lane][8 j] f16  = 294912 B
//   w0frag  @ 294912 : [4 ot][64 lane][8 j]          f16  = 4096 B   (K padded 4->16)
//   biasC   @ 299008 : [10 l][4 ot][2 h][16 r]       f32  = 5120 B   (MFMA C-operand order)
//   woutf16 @ 304128 : [8 kt][64 lane][8 j]          f16  = 8192 B   (A-frag, rows!=0 zeroed)
// fragment value convention (32x32x16 f16 MFMA):
//   A lane l holds row i = l&31, k = (l>>5)*8 + j
//   B lane l holds col j = l&31, k = (l>>5)*8 + j
//   D/C lane l holds col = l&31, row = (r&3) + 8*(r>>2) + 4*(l>>5)
__global__ void prep_kernel(const float* __restrict__ W0, const float* __restrict__ b0,
                            const float* __restrict__ Wh, const float* __restrict__ bh,
                            const float* __restrict__ Wout,
                            _Float16* __restrict__ wfrag, _Float16* __restrict__ w0frag,
                            float* __restrict__ biasC, _Float16* __restrict__ woutf16) {
  const int stride = gridDim.x * blockDim.x;
  for (int idx = blockIdx.x * blockDim.x + threadIdx.x; idx < 154880; idx += stride) {
    if (idx < 147456) {                       // wfrag: Wh[l][o][k] -> A-fragment order
      const int j = idx & 7, lane = (idx >> 3) & 63, kt = (idx >> 9) & 7,
                ot = (idx >> 12) & 3, l = idx >> 14;
      const int o = ot * 32 + (lane & 31);
      const int k = kt * 16 + (lane >> 5) * 8 + j;
      wfrag[idx] = (_Float16)Wh[(l * 128 + o) * 128 + k];
    } else if (idx < 147456 + 2048) {         // w0frag (K padded with zeros)
      const int i = idx - 147456;
      const int j = i & 7, lane = (i >> 3) & 63, ot = i >> 9;
      const int o = ot * 32 + (lane & 31);
      const int k = (lane >> 5) * 8 + j;
      w0frag[i] = (_Float16)(k < 4 ? W0[o * 4 + k] : 0.0f);
    } else if (idx < 147456 + 2048 + 1280) {  // biasC: C-operand order per (l,ot,h)
      const int i = idx - (147456 + 2048);
      const int r = i & 15, hh = (i >> 4) & 1, ot = (i >> 5) & 3, l = i >> 7;
      const int row = (r & 3) + 8 * (r >> 2) + 4 * hh;
      const int o = ot * 32 + row;
      biasC[i] = (l == 0) ? b0[o] : bh[(l - 1) * 128 + o];
    } else {                                  // Wout as masked A-fragment (row 0 only), f16
      const int i = idx - (147456 + 2048 + 1280);
      const int j = i & 7, lane = (i >> 3) & 63, kt = i >> 9;
      const int k = kt * 16 + (lane >> 5) * 8 + j;
      woutf16[i] = ((lane & 31) == 0) ? (_Float16)Wout[k] : (_Float16)0.0f;
    }
  }
}

// ---------------- fused MLP: 512 threads, 8 waves x 32 rows, nt=1 ----------------
// Register budget per wave (unified VGPR+AGPR): acc 64 + B 32 + ~30 misc ~= 126
// -> 4 waves/SIMD (16 waves/CU). Cross-wave phase stagger hides epilogue VALU and
// ds_read latency under the matrix pipe; barriers only gate the W double-buffer.
__global__ __launch_bounds__(512, 4) void mlp_fused(
    const float* __restrict__ x,
    const _Float16* __restrict__ wfrag,
    const _Float16* __restrict__ w0frag,
    const float* __restrict__ biasCg,
    const _Float16* __restrict__ woutf16,
    const float* __restrict__ boutp,
    float* __restrict__ out) {
  // 2 x 32 KB W double-buffer + bias C-table; 70.7 KB -> 2 blocks/CU
  __shared__ __align__(16) unsigned char ldsW[2][32768];
  __shared__ __align__(16) float ldsBiasC[1280];

  const int t    = threadIdx.x;
  const int lane = t & 63;
  const int wv   = t >> 6;       // 0..7
  const int h    = lane >> 5;    // half-wave
  const int ln   = lane & 31;
  const long rowbase = (long)blockIdx.x * 256 + wv * 32;  // 32 rows per wave

  // ---- prologue staging: W[1] -> ldsW[0]; bias C-table ----
  {
    const unsigned char* src = (const unsigned char*)wfrag;  // layer 1 at offset 0
#pragma unroll
    for (int i = 0; i < 4; ++i) {  // 512 thr * 16 B * 4 = 32 KB
      const int off = i * 8192 + t * 16;
      g2lds16(src + off, &ldsW[0][off]);
    }
    if (t < 320) {  // 5120 B of bias C-table
      const unsigned char* bsrc = (const unsigned char*)biasCg;
      g2lds16(bsrc + t * 16, (unsigned char*)ldsBiasC + t * 16);
    }
  }

  Frag   B[8];       // current-layer input fragments (H^T), per k-tile
  f32x16 acc[4];     // [o-tile], D = H_out^T (32 cols x 32 rows each)
  const f32x16 fzero = (f32x16)0.0f;

  // broadcast read of the per-(layer,ot,half) C-operand (bias pre-placed in D order)
  auto load_cvec = [&](int l, int ot) -> f32x16 {
    CVec cv;
    const float* p = ldsBiasC + ((l * 4 + ot) * 2 + h) * 16;
#pragma unroll
    for (int g = 0; g < 4; ++g) cv.q[g] = *(const float4*)(p + g * 4);
    return cv.v;
  };

  // E-chunk: relu+pack acc[ot] (bias already inside), permlane32 half-exchange,
  // writes B[2ot], B[2ot+1]. Register-only; all indices compile-time.
  auto e_chunk = [&](int ot) {
    uint32_t P[4][2];
#pragma unroll
    for (int g = 0; g < 4; ++g) {
#pragma unroll
      for (int c = 0; c < 2; ++c) {
        const uint32_t cv = pkrtz(acc[ot][g * 4 + c * 2 + 0],
                                  acc[ot][g * 4 + c * 2 + 1]);
        uint32_t r;
        asm("v_pk_max_f16 %0, %1, %2" : "=v"(r) : "v"(cv), "v"(0u));
        P[g][c] = r;
      }
    }
#pragma unroll
    for (int u = 0; u < 2; ++u) {
      uint32_t a0 = P[2 * u][0], b0v = P[2 * u + 1][0];
      uint32_t a1 = P[2 * u][1], b1v = P[2 * u + 1][1];
      asm("v_permlane32_swap_b32 %0, %1" : "+v"(a0), "+v"(b0v));
      asm("v_permlane32_swap_b32 %0, %1" : "+v"(a1), "+v"(b1v));
      Frag nb;
      nb.w[0] = a0;   // h==0: own lo pair | h==1: partner's lo pair
      nb.w[1] = a1;
      nb.w[2] = b0v;  // h==0: partner's hi pair | h==1: own hi pair
      nb.w[3] = b1v;
      B[ot * 2 + u] = nb;
    }
  };

  // x loads + pack overlap the staging latency (this wave's 32 rows)
  Frag xb;
  {
    float4 xv = make_float4(0.f, 0.f, 0.f, 0.f);
    if (h == 0) xv = *(const float4*)(x + (rowbase + ln) * 4);
    xb.w[0] = pack2h(xv.x, xv.y);
    xb.w[1] = pack2h(xv.z, xv.w);
    xb.w[2] = 0u;
    xb.w[3] = 0u;
  }

  __syncthreads();  // staging drained (implicit vmcnt(0) lgkmcnt(0) before barrier)

  // ---- layer 0: K=16 zero-padded MFMA, C = bias ----
#pragma unroll
  for (int ot = 0; ot < 4; ++ot) {
    const f16x8 a0 = *(const f16x8*)(w0frag + ot * 512 + lane * 8);
    const f32x16 cvec = load_cvec(0, ot);
    acc[ot] = __builtin_amdgcn_mfma_f32_32x32x16_f16(a0, xb.v, cvec, 0, 0, 0);
  }
  // NOTE: no barrier here — layer 1 reads ldsW[0], drained at the barrier above.

  // ---- rotated pipeline: R(l) = {prefetch W[l+1]; epilogue(l-1); MFMA(l); barrier} ----
#pragma unroll
  for (int l = 1; l <= 9; ++l) {
    if (l < 9) {  // prefetch W[l+1] into buf[l&1] (last read by layer l-1, pre-barrier)
      const unsigned char* src = (const unsigned char*)wfrag + (size_t)l * 32768;
#pragma unroll
      for (int i = 0; i < 4; ++i) {
        const int off = i * 8192 + t * 16;
        g2lds16(src + off, &ldsW[l & 1][off]);
      }
    }
#pragma unroll
    for (int c = 0; c < 4; ++c) e_chunk(c);  // acc(l-1) -> B (register-only)
    const unsigned char* wl = &ldsW[(l - 1) & 1][0];
    __builtin_amdgcn_s_setprio(1);
#pragma unroll
    for (int kt = 0; kt < 8; ++kt) {
#pragma unroll
      for (int ot = 0; ot < 4; ++ot) {
        const f16x8 a = *(const f16x8*)(wl + ot * 8192 + kt * 1024 + lane * 16);
        if (kt == 0) {
          const f32x16 cvec = load_cvec(l, ot);
          acc[ot] = __builtin_amdgcn_mfma_f32_32x32x16_f16(a, B[0].v, cvec, 0, 0, 0);
        } else {
          acc[ot] = __builtin_amdgcn_mfma_f32_32x32x16_f16(a, B[kt].v, acc[ot], 0, 0, 0);
        }
      }
    }
    __builtin_amdgcn_s_setprio(0);
    if (l < 9) __syncthreads();  // gates buf reuse; drains prefetch W[l+1]
  }

  // ---- output layer: MFMA with masked Wout A-fragment (row 0 only) ----
  // D row 0 lives in reg 0 of lanes 0..31 -> no shuffle reduce needed.
  {
    Frag wa[8];
#pragma unroll
    for (int kt = 0; kt < 8; ++kt)
      wa[kt].v = *(const f16x8*)(woutf16 + kt * 512 + lane * 8);
    const float boutv = *boutp;

#pragma unroll
    for (int c = 0; c < 4; ++c) e_chunk(c);  // layer 9 acc -> B

    f32x16 accO = fzero;
#pragma unroll
    for (int kt = 0; kt < 8; ++kt)
      accO = __builtin_amdgcn_mfma_f32_32x32x16_f16(wa[kt].v, B[kt].v, accO, 0, 0, 0);
    if (h == 0) out[rowbase + ln] = accO[0] + boutv;
  }
}

extern "C" void kernel_launch(void* const* d_in, const int* in_sizes, int n_in,
                              void* d_out, int out_size, void* d_ws, size_t ws_size,
                              hipStream_t stream) {
  (void)n_in; (void)out_size; (void)ws_size;  // needs ~313 KB of ws
  const float* x    = (const float*)d_in[0];
  const float* W0   = (const float*)d_in[1];
  const float* b0   = (const float*)d_in[2];
  const float* Wh   = (const float*)d_in[3];
  const float* bh   = (const float*)d_in[4];
  const float* Wout = (const float*)d_in[5];
  const float* bout = (const float*)d_in[6];
  float* out = (float*)d_out;

  char* ws = (char*)d_ws;
  _Float16* wfrag   = (_Float16*)(ws);
  _Float16* w0frag  = (_Float16*)(ws + 294912);
  float*    biasC   = (float*)(ws + 299008);
  _Float16* woutf16 = (_Float16*)(ws + 304128);

  const int n = in_sizes[0] / 4;  // 1048576 points

  prep_kernel<<<dim3(160), dim3(256), 0, stream>>>(W0, b0, Wh, bh, Wout,
                                                   wfrag, w0frag, biasC, woutf16);
  mlp_fused<<<dim3(n / 256), dim3(512), 0, stream>>>(x, wfrag, w0frag, biasC,
                                                     woutf16, bout, out);
}

// Round 9
// 251.902 us; speedup vs baseline: 1.1398x; 1.0689x over previous
//
#include <hip/hip_runtime.h>
#include <stdint.h>

// ---------------- types ----------------
typedef _Float16 f16x8 __attribute__((ext_vector_type(8)));
typedef __fp16   fp16x2 __attribute__((ext_vector_type(2)));
typedef float    f32x16 __attribute__((ext_vector_type(16)));

union Frag {
  f16x8    v;
  uint32_t w[4];
  _Float16 h[8];
};

union CVec {
  float4 q[4];
  f32x16 v;
};

__device__ __forceinline__ uint32_t pack2h(float a, float b) {
  union { _Float16 h[2]; uint32_t u; } r;
  r.h[0] = (_Float16)a;   // RNE f32->f16
  r.h[1] = (_Float16)b;
  return r.u;
}

__device__ __forceinline__ uint32_t pkrtz(float a, float b) {
  union { fp16x2 h2; uint32_t u; } cv;
  cv.h2 = __builtin_amdgcn_cvt_pkrtz(a, b);
  return cv.u;
}

__device__ __forceinline__ void g2lds16(const void* g, void* l) {
  __builtin_amdgcn_global_load_lds(
      (const __attribute__((address_space(1))) uint32_t*)g,
      (__attribute__((address_space(3))) uint32_t*)l, 16, 0, 0);
}

// Channel relabeling (involution) applied to W rows + bias of EVERY layer:
// slot s (0..31 within a 32-tile) holds logical channel lam32(s).
// With this, D-reg pairs are already in B-fragment k-order -> NO lane exchange.
__host__ __device__ __forceinline__ int lam32(int s) {
  return (((s >> 2) ^ (s >> 3)) & 1) ? (s ^ 12) : s;
}

// ---------------- prep: fragment-order the weights (f16) ----------------
// ws layout (bytes):
//   wfrag   @ 0      : [9][4 ot][8 kt][64 lane][8 j] f16  = 294912 B
//   w0frag  @ 294912 : [4 ot][64 lane][8 j]          f16  = 4096 B   (K padded 4->16)
//   biasC   @ 299008 : [10 l][4 ot][2 h][16 r]       f32  = 5120 B   (MFMA C-operand order)
//   woutf16 @ 304128 : [8 kt][64 lane][8 j]          f16  = 8192 B   (A-frag, rows!=0 zeroed)
// fragment value convention (32x32x16 f16 MFMA):
//   A lane l holds row i = l&31, k = (l>>5)*8 + j
//   B lane l holds col j = l&31, k = (l>>5)*8 + j
//   D/C lane l holds col = l&31, row r: slot = (r&3) + 8*(r>>2) + 4*(l>>5)
// Rows of W/bias are stored at slot s holding logical channel lam32(s), so that
// logical(ot,h,r) = ot*32 + 16*(r>>3) + 8*h + (r&7) — adjacent acc pairs pack
// directly into next-layer B fragments. W columns stay logical (B is logical).
__global__ void prep_kernel(const float* __restrict__ W0, const float* __restrict__ b0,
                            const float* __restrict__ Wh, const float* __restrict__ bh,
                            const float* __restrict__ Wout,
                            _Float16* __restrict__ wfrag, _Float16* __restrict__ w0frag,
                            float* __restrict__ biasC, _Float16* __restrict__ woutf16) {
  const int stride = gridDim.x * blockDim.x;
  for (int idx = blockIdx.x * blockDim.x + threadIdx.x; idx < 154880; idx += stride) {
    if (idx < 147456) {                       // wfrag: Wh[l][lam(o)][k] -> A-fragment order
      const int j = idx & 7, lane = (idx >> 3) & 63, kt = (idx >> 9) & 7,
                ot = (idx >> 12) & 3, l = idx >> 14;
      const int o = ot * 32 + lam32(lane & 31);
      const int k = kt * 16 + (lane >> 5) * 8 + j;
      wfrag[idx] = (_Float16)Wh[(l * 128 + o) * 128 + k];
    } else if (idx < 147456 + 2048) {         // w0frag (K padded with zeros), rows lam'd
      const int i = idx - 147456;
      const int j = i & 7, lane = (i >> 3) & 63, ot = i >> 9;
      const int o = ot * 32 + lam32(lane & 31);
      const int k = (lane >> 5) * 8 + j;
      w0frag[i] = (_Float16)(k < 4 ? W0[o * 4 + k] : 0.0f);
    } else if (idx < 147456 + 2048 + 1280) {  // biasC: C-operand order per (l,ot,h), lam'd
      const int i = idx - (147456 + 2048);
      const int r = i & 15, hh = (i >> 4) & 1, ot = (i >> 5) & 3, l = i >> 7;
      const int slot = (r & 3) + 8 * (r >> 2) + 4 * hh;
      const int o = ot * 32 + lam32(slot);
      biasC[i] = (l == 0) ? b0[o] : bh[(l - 1) * 128 + o];
    } else {                                  // Wout as masked A-fragment (row 0 only), f16
      const int i = idx - (147456 + 2048 + 1280);
      const int j = i & 7, lane = (i >> 3) & 63, kt = i >> 9;
      const int k = kt * 16 + (lane >> 5) * 8 + j;   // logical k — unchanged
      woutf16[i] = ((lane & 31) == 0) ? (_Float16)Wout[k] : (_Float16)0.0f;
    }
  }
}

// ---------------- fused MLP: 256 threads, 4 waves x 64 rows (nt=2) ----------------
__global__ __launch_bounds__(256, 2) void mlp_fused(
    const float* __restrict__ x,
    const _Float16* __restrict__ wfrag,
    const _Float16* __restrict__ w0frag,
    const float* __restrict__ biasCg,
    const _Float16* __restrict__ woutf16,
    const float* __restrict__ boutp,
    float* __restrict__ out) {
  // 2 x 32 KB W double-buffer + bias C-table; 70.7 KB -> 2 blocks/CU
  __shared__ __align__(16) unsigned char ldsW[2][32768];
  __shared__ __align__(16) float ldsBiasC[1280];

  const int t    = threadIdx.x;
  const int lane = t & 63;
  const int wv   = t >> 6;
  const int h    = lane >> 5;   // half-wave
  const int ln   = lane & 31;
  const long rowbase = (long)blockIdx.x * 256 + wv * 64;  // + nt*32 + ln

  // ---- prologue staging: W[1] -> ldsW[0]; bias C-table ----
  {
    const unsigned char* src = (const unsigned char*)wfrag;  // layer 1 at offset 0
#pragma unroll
    for (int i = 0; i < 8; ++i) {
      const int off = i * 4096 + t * 16;
      g2lds16(src + off, &ldsW[0][off]);
    }
    const unsigned char* bsrc = (const unsigned char*)biasCg;
    g2lds16(bsrc + t * 16, (unsigned char*)ldsBiasC + t * 16);            // chunks 0..255
    if (t < 64) g2lds16(bsrc + (256 + t) * 16, (unsigned char*)ldsBiasC + (256 + t) * 16);
  }

  Frag   B[2][8];      // current-layer input fragments (H^T), per nt / k-tile
  f32x16 acc[4][2];    // [o-tile][n-tile], D = H_out^T
  const f32x16 fzero = (f32x16)0.0f;

  // broadcast read of the per-(layer,ot,half) C-operand (bias pre-placed in D order)
  auto load_cvec = [&](int l, int ot) -> f32x16 {
    CVec cv;
    const float* p = ldsBiasC + ((l * 4 + ot) * 2 + h) * 16;
#pragma unroll
    for (int g = 0; g < 4; ++g) cv.q[g] = *(const float4*)(p + g * 4);
    return cv.v;
  };

  // x loads + pack overlap the staging latency
  Frag xb[2];
#pragma unroll
  for (int nt = 0; nt < 2; ++nt) {
    float4 xv = make_float4(0.f, 0.f, 0.f, 0.f);
    if (h == 0) xv = *(const float4*)(x + (rowbase + nt * 32 + ln) * 4);
    xb[nt].w[0] = pack2h(xv.x, xv.y);
    xb[nt].w[1] = pack2h(xv.z, xv.w);
    xb[nt].w[2] = 0u;
    xb[nt].w[3] = 0u;
  }

  __syncthreads();  // staging drained (implicit vmcnt(0) lgkmcnt(0) before barrier)

  // ---- layer 0: K=16 zero-padded MFMA, C = bias ----
#pragma unroll
  for (int ot = 0; ot < 4; ++ot) {
    const f16x8 a0 = *(const f16x8*)(w0frag + ot * 512 + lane * 8);
    const f32x16 cvec = load_cvec(0, ot);
    acc[ot][0] = __builtin_amdgcn_mfma_f32_32x32x16_f16(a0, xb[0].v, cvec, 0, 0, 0);
    acc[ot][1] = __builtin_amdgcn_mfma_f32_32x32x16_f16(a0, xb[1].v, cvec, 0, 0, 0);
  }
  // NOTE: no barrier here — layer 1 reads ldsW[0], drained at the barrier above.

  // epilogue: relu+pack straight from acc pairs (lam32 pre-permutation makes the
  // D-reg order equal the B-fragment k-order — no lane exchange, no moves).
  auto do_epilogue = [&]() {
#pragma unroll
    for (int ot = 0; ot < 4; ++ot) {
#pragma unroll
      for (int nt = 0; nt < 2; ++nt) {
#pragma unroll
        for (int u = 0; u < 2; ++u) {      // B k-tile half: acc regs 8u..8u+7
          Frag nb;
#pragma unroll
          for (int j = 0; j < 4; ++j) {
            const uint32_t cv = pkrtz(acc[ot][nt][8 * u + 2 * j],
                                      acc[ot][nt][8 * u + 2 * j + 1]);
            uint32_t r;
            asm("v_pk_max_f16 %0, %1, %2" : "=v"(r) : "v"(cv), "v"(0u));
            nb.w[j] = r;
          }
          B[nt][ot * 2 + u] = nb;
        }
      }
    }
  };

  // ---- rotated pipeline: R(l) = {prefetch W[l+1]; epilogue(l-1); MFMA(l); barrier} ----
#pragma unroll
  for (int l = 1; l <= 9; ++l) {
    if (l < 9) {  // prefetch W[l+1] into buf[l&1] (last read by layer l-1, pre-barrier)
      const unsigned char* src = (const unsigned char*)wfrag + (size_t)l * 32768;
#pragma unroll
      for (int i = 0; i < 8; ++i) {
        const int off = i * 4096 + t * 16;
        g2lds16(src + off, &ldsW[l & 1][off]);
      }
    }
    do_epilogue();  // acc(l-1) -> B (register-only; overlaps loads below)
    const unsigned char* wl = &ldsW[(l - 1) & 1][0];
    __builtin_amdgcn_s_setprio(1);
#pragma unroll
    for (int kt = 0; kt < 8; ++kt) {
#pragma unroll
      for (int ot = 0; ot < 4; ++ot) {
        const f16x8 a = *(const f16x8*)(wl + ot * 8192 + kt * 1024 + lane * 16);
        if (kt == 0) {
          const f32x16 cvec = load_cvec(l, ot);
          acc[ot][0] = __builtin_amdgcn_mfma_f32_32x32x16_f16(a, B[0][kt].v, cvec, 0, 0, 0);
          acc[ot][1] = __builtin_amdgcn_mfma_f32_32x32x16_f16(a, B[1][kt].v, cvec, 0, 0, 0);
        } else {
          acc[ot][0] = __builtin_amdgcn_mfma_f32_32x32x16_f16(a, B[0][kt].v, acc[ot][0], 0, 0, 0);
          acc[ot][1] = __builtin_amdgcn_mfma_f32_32x32x16_f16(a, B[1][kt].v, acc[ot][1], 0, 0, 0);
        }
      }
    }
    __builtin_amdgcn_s_setprio(0);
    if (l < 9) __syncthreads();  // gates buf reuse; drains prefetch W[l+1]
  }

  // ---- output layer: MFMA with masked Wout A-fragment (row 0 only) ----
  // D row 0 lives in reg 0 of lanes 0..31 -> no shuffle reduce needed.
  {
    Frag wa[8];
#pragma unroll
    for (int kt = 0; kt < 8; ++kt)
      wa[kt].v = *(const f16x8*)(woutf16 + kt * 512 + lane * 8);
    const float boutv = *boutp;

    do_epilogue();  // layer 9 acc -> B

    f32x16 accO0 = fzero, accO1 = fzero;
#pragma unroll
    for (int kt = 0; kt < 8; ++kt) {
      accO0 = __builtin_amdgcn_mfma_f32_32x32x16_f16(wa[kt].v, B[0][kt].v, accO0, 0, 0, 0);
      accO1 = __builtin_amdgcn_mfma_f32_32x32x16_f16(wa[kt].v, B[1][kt].v, accO1, 0, 0, 0);
    }
    if (h == 0) {
      out[rowbase + ln]      = accO0[0] + boutv;
      out[rowbase + 32 + ln] = accO1[0] + boutv;
    }
  }
}

extern "C" void kernel_launch(void* const* d_in, const int* in_sizes, int n_in,
                              void* d_out, int out_size, void* d_ws, size_t ws_size,
                              hipStream_t stream) {
  (void)n_in; (void)out_size; (void)ws_size;  // needs ~313 KB of ws
  const float* x    = (const float*)d_in[0];
  const float* W0   = (const float*)d_in[1];
  const float* b0   = (const float*)d_in[2];
  const float* Wh   = (const float*)d_in[3];
  const float* bh   = (const float*)d_in[4];
  const float* Wout = (const float*)d_in[5];
  const float* bout = (const float*)d_in[6];
  float* out = (float*)d_out;

  char* ws = (char*)d_ws;
  _Float16* wfrag   = (_Float16*)(ws);
  _Float16* w0frag  = (_Float16*)(ws + 294912);
  float*    biasC   = (float*)(ws + 299008);
  _Float16* woutf16 = (_Float16*)(ws + 304128);

  const int n = in_sizes[0] / 4;  // 1048576 points

  prep_kernel<<<dim3(160), dim3(256), 0, stream>>>(W0, b0, Wh, bh, Wout,
                                                   wfrag, w0frag, biasC, woutf16);
  mlp_fused<<<dim3(n / 256), dim3(256), 0, stream>>>(x, wfrag, w0frag, biasC,
                                                     woutf16, bout, out);
}

// Round 10
// 250.515 us; speedup vs baseline: 1.1461x; 1.0055x over previous
//
#include <hip/hip_runtime.h>
#include <stdint.h>

// ---------------- types ----------------
typedef _Float16 f16x8 __attribute__((ext_vector_type(8)));
typedef __fp16   fp16x2 __attribute__((ext_vector_type(2)));
typedef float    f32x16 __attribute__((ext_vector_type(16)));

union Frag {
  f16x8    v;
  uint32_t w[4];
  _Float16 h[8];
};

union CVec {
  float4 q[4];
  f32x16 v;
};

__device__ __forceinline__ uint32_t pack2h(float a, float b) {
  union { _Float16 h[2]; uint32_t u; } r;
  r.h[0] = (_Float16)a;   // RNE f32->f16
  r.h[1] = (_Float16)b;
  return r.u;
}

__device__ __forceinline__ uint32_t pkrtz(float a, float b) {
  union { fp16x2 h2; uint32_t u; } cv;
  cv.h2 = __builtin_amdgcn_cvt_pkrtz(a, b);
  return cv.u;
}

__device__ __forceinline__ void g2lds16(const void* g, void* l) {
  __builtin_amdgcn_global_load_lds(
      (const __attribute__((address_space(1))) uint32_t*)g,
      (__attribute__((address_space(3))) uint32_t*)l, 16, 0, 0);
}

// Channel relabeling (involution) applied to W rows + bias of EVERY layer:
// slot s (0..31 within a 32-tile) holds logical channel lam32(s).
// With this, D-reg pairs are already in B-fragment k-order -> NO lane exchange.
__host__ __device__ __forceinline__ int lam32(int s) {
  return (((s >> 2) ^ (s >> 3)) & 1) ? (s ^ 12) : s;
}

// ---------------- prep: fragment-order the weights (f16) ----------------
// ws layout (bytes):
//   wfrag   @ 0      : [9][4 ot][8 kt][64 lane][8 j] f16  = 294912 B
//   w0frag  @ 294912 : [4 ot][64 lane][8 j]          f16  = 4096 B   (K padded 4->16)
//   biasC   @ 299008 : [10 l][4 ot][2 h][16 r]       f32  = 5120 B   (MFMA C-operand order)
//   woutf16 @ 304128 : [8 kt][64 lane][8 j]          f16  = 8192 B   (A-frag, rows!=0 zeroed)
// fragment value convention (32x32x16 f16 MFMA):
//   A lane l holds row i = l&31, k = (l>>5)*8 + j
//   B lane l holds col j = l&31, k = (l>>5)*8 + j
//   D/C lane l holds col = l&31, row r: slot = (r&3) + 8*(r>>2) + 4*(l>>5)
// Rows of W/bias are stored at slot s holding logical channel lam32(s), so that
// logical(ot,h,r) = ot*32 + 16*(r>>3) + 8*h + (r&7) — adjacent acc pairs pack
// directly into next-layer B fragments. W columns stay logical (B is logical).
__global__ void prep_kernel(const float* __restrict__ W0, const float* __restrict__ b0,
                            const float* __restrict__ Wh, const float* __restrict__ bh,
                            const float* __restrict__ Wout,
                            _Float16* __restrict__ wfrag, _Float16* __restrict__ w0frag,
                            float* __restrict__ biasC, _Float16* __restrict__ woutf16) {
  const int stride = gridDim.x * blockDim.x;
  for (int idx = blockIdx.x * blockDim.x + threadIdx.x; idx < 154880; idx += stride) {
    if (idx < 147456) {                       // wfrag: Wh[l][lam(o)][k] -> A-fragment order
      const int j = idx & 7, lane = (idx >> 3) & 63, kt = (idx >> 9) & 7,
                ot = (idx >> 12) & 3, l = idx >> 14;
      const int o = ot * 32 + lam32(lane & 31);
      const int k = kt * 16 + (lane >> 5) * 8 + j;
      wfrag[idx] = (_Float16)Wh[(l * 128 + o) * 128 + k];
    } else if (idx < 147456 + 2048) {         // w0frag (K padded with zeros), rows lam'd
      const int i = idx - 147456;
      const int j = i & 7, lane = (i >> 3) & 63, ot = i >> 9;
      const int o = ot * 32 + lam32(lane & 31);
      const int k = (lane >> 5) * 8 + j;
      w0frag[i] = (_Float16)(k < 4 ? W0[o * 4 + k] : 0.0f);
    } else if (idx < 147456 + 2048 + 1280) {  // biasC: C-operand order per (l,ot,h), lam'd
      const int i = idx - (147456 + 2048);
      const int r = i & 15, hh = (i >> 4) & 1, ot = (i >> 5) & 3, l = i >> 7;
      const int slot = (r & 3) + 8 * (r >> 2) + 4 * hh;
      const int o = ot * 32 + lam32(slot);
      biasC[i] = (l == 0) ? b0[o] : bh[(l - 1) * 128 + o];
    } else {                                  // Wout as masked A-fragment (row 0 only), f16
      const int i = idx - (147456 + 2048 + 1280);
      const int j = i & 7, lane = (i >> 3) & 63, kt = i >> 9;
      const int k = kt * 16 + (lane >> 5) * 8 + j;   // logical k — unchanged
      woutf16[i] = ((lane & 31) == 0) ? (_Float16)Wout[k] : (_Float16)0.0f;
    }
  }
}

// ---------------- fused MLP: 256 threads, 4 waves x 64 rows (nt=2) ----------------
__global__ __launch_bounds__(256, 2) void mlp_fused(
    const float* __restrict__ x,
    const _Float16* __restrict__ wfrag,
    const _Float16* __restrict__ w0frag,
    const float* __restrict__ biasCg,
    const _Float16* __restrict__ woutf16,
    const float* __restrict__ boutp,
    float* __restrict__ out) {
  // 2 x 32 KB W double-buffer + bias C-table; 70.7 KB -> 2 blocks/CU
  __shared__ __align__(16) unsigned char ldsW[2][32768];
  __shared__ __align__(16) float ldsBiasC[1280];

  const int t    = threadIdx.x;
  const int lane = t & 63;
  const int wv   = t >> 6;
  const int h    = lane >> 5;   // half-wave
  const int ln   = lane & 31;
  const long rowbase = (long)blockIdx.x * 256 + wv * 64;  // + nt*32 + ln

  // ---- prologue staging: W[1] -> ldsW[0]; bias C-table ----
  {
    const unsigned char* src = (const unsigned char*)wfrag;  // layer 1 at offset 0
#pragma unroll
    for (int i = 0; i < 8; ++i) {
      const int off = i * 4096 + t * 16;
      g2lds16(src + off, &ldsW[0][off]);
    }
    const unsigned char* bsrc = (const unsigned char*)biasCg;
    g2lds16(bsrc + t * 16, (unsigned char*)ldsBiasC + t * 16);            // chunks 0..255
    if (t < 64) g2lds16(bsrc + (256 + t) * 16, (unsigned char*)ldsBiasC + (256 + t) * 16);
  }

  Frag   B[2][8];      // current-layer input fragments (H^T), per nt / k-tile
  f32x16 acc[4][2];    // [o-tile][n-tile], D = H_out^T
  const f32x16 fzero = (f32x16)0.0f;

  // broadcast read of the per-(layer,ot,half) C-operand (bias pre-placed in D order)
  auto load_cvec = [&](int l, int ot) -> f32x16 {
    CVec cv;
    const float* p = ldsBiasC + ((l * 4 + ot) * 2 + h) * 16;
#pragma unroll
    for (int g = 0; g < 4; ++g) cv.q[g] = *(const float4*)(p + g * 4);
    return cv.v;
  };

  // x loads + pack overlap the staging latency
  Frag xb[2];
#pragma unroll
  for (int nt = 0; nt < 2; ++nt) {
    float4 xv = make_float4(0.f, 0.f, 0.f, 0.f);
    if (h == 0) xv = *(const float4*)(x + (rowbase + nt * 32 + ln) * 4);
    xb[nt].w[0] = pack2h(xv.x, xv.y);
    xb[nt].w[1] = pack2h(xv.z, xv.w);
    xb[nt].w[2] = 0u;
    xb[nt].w[3] = 0u;
  }

  __syncthreads();  // staging drained (implicit vmcnt(0) lgkmcnt(0) before barrier)

  // ---- layer 0: K=16 zero-padded MFMA, C = bias ----
#pragma unroll
  for (int ot = 0; ot < 4; ++ot) {
    const f16x8 a0 = *(const f16x8*)(w0frag + ot * 512 + lane * 8);
    const f32x16 cvec = load_cvec(0, ot);
    acc[ot][0] = __builtin_amdgcn_mfma_f32_32x32x16_f16(a0, xb[0].v, cvec, 0, 0, 0);
    acc[ot][1] = __builtin_amdgcn_mfma_f32_32x32x16_f16(a0, xb[1].v, cvec, 0, 0, 0);
  }
  // NOTE: no barrier here — layer 1 reads ldsW[0], drained at the barrier above.

  // epilogue: relu+pack straight from acc pairs (lam32 pre-permutation makes the
  // D-reg order equal the B-fragment k-order — no lane exchange, no moves).
  auto do_epilogue = [&]() {
#pragma unroll
    for (int ot = 0; ot < 4; ++ot) {
#pragma unroll
      for (int nt = 0; nt < 2; ++nt) {
#pragma unroll
        for (int u = 0; u < 2; ++u) {      // B k-tile half: acc regs 8u..8u+7
          Frag nb;
#pragma unroll
          for (int j = 0; j < 4; ++j) {
            const uint32_t cv = pkrtz(acc[ot][nt][8 * u + 2 * j],
                                      acc[ot][nt][8 * u + 2 * j + 1]);
            uint32_t r;
            asm("v_pk_max_f16 %0, %1, %2" : "=v"(r) : "v"(cv), "v"(0u));
            nb.w[j] = r;
          }
          B[nt][ot * 2 + u] = nb;
        }
      }
    }
  };

  // ---- rotated pipeline: R(l) = {prefetch W[l+1]; epilogue(l-1); MFMA(l); barrier} ----
  // Inside MFMA(l): rotating A-fragment pipeline — refill a[ot] with the (kt+1)
  // fragment right after its two MFMAs consume it (zero extra registers; ~6 MFMAs
  // of slack cover the ds_read latency). sched_group_barrier pins the
  // {2 MFMA, 1 ds_read} interleave so LDS and matrix pipes run concurrently.
#pragma unroll
  for (int l = 1; l <= 9; ++l) {
    if (l < 9) {  // prefetch W[l+1] into buf[l&1] (last read by layer l-1, pre-barrier)
      const unsigned char* src = (const unsigned char*)wfrag + (size_t)l * 32768;
#pragma unroll
      for (int i = 0; i < 8; ++i) {
        const int off = i * 4096 + t * 16;
        g2lds16(src + off, &ldsW[l & 1][off]);
      }
    }
    do_epilogue();  // acc(l-1) -> B (register-only; overlaps load issue)
    const unsigned char* wl = &ldsW[(l - 1) & 1][0];

    f16x8 a[4];
#pragma unroll
    for (int ot = 0; ot < 4; ++ot)   // preload kt=0 fragments
      a[ot] = *(const f16x8*)(wl + ot * 8192 + lane * 16);

#pragma unroll
    for (int kt = 0; kt < 8; ++kt) {
#pragma unroll
      for (int ot = 0; ot < 4; ++ot) {
        if (kt == 0) {
          const f32x16 cvec = load_cvec(l, ot);
          acc[ot][0] = __builtin_amdgcn_mfma_f32_32x32x16_f16(a[ot], B[0][kt].v, cvec, 0, 0, 0);
          acc[ot][1] = __builtin_amdgcn_mfma_f32_32x32x16_f16(a[ot], B[1][kt].v, cvec, 0, 0, 0);
        } else {
          acc[ot][0] = __builtin_amdgcn_mfma_f32_32x32x16_f16(a[ot], B[0][kt].v, acc[ot][0], 0, 0, 0);
          acc[ot][1] = __builtin_amdgcn_mfma_f32_32x32x16_f16(a[ot], B[1][kt].v, acc[ot][1], 0, 0, 0);
        }
        if (kt < 7)   // refill the just-freed fragment register with kt+1's data
          a[ot] = *(const f16x8*)(wl + ot * 8192 + (kt + 1) * 1024 + lane * 16);
        // pin interleave: 2 MFMAs then 1 ds_read per ot-step
        __builtin_amdgcn_sched_group_barrier(0x008, 2, 0);  // MFMA
        if (kt < 7)
          __builtin_amdgcn_sched_group_barrier(0x100, 1, 0);  // DS_READ
      }
    }
    if (l < 9) __syncthreads();  // gates buf reuse; drains prefetch W[l+1]
  }

  // ---- output layer: MFMA with masked Wout A-fragment (row 0 only) ----
  // D row 0 lives in reg 0 of lanes 0..31 -> no shuffle reduce needed.
  {
    Frag wa[8];
#pragma unroll
    for (int kt = 0; kt < 8; ++kt)
      wa[kt].v = *(const f16x8*)(woutf16 + kt * 512 + lane * 8);
    const float boutv = *boutp;

    do_epilogue();  // layer 9 acc -> B

    f32x16 accO0 = fzero, accO1 = fzero;
#pragma unroll
    for (int kt = 0; kt < 8; ++kt) {
      accO0 = __builtin_amdgcn_mfma_f32_32x32x16_f16(wa[kt].v, B[0][kt].v, accO0, 0, 0, 0);
      accO1 = __builtin_amdgcn_mfma_f32_32x32x16_f16(wa[kt].v, B[1][kt].v, accO1, 0, 0, 0);
    }
    if (h == 0) {
      out[rowbase + ln]      = accO0[0] + boutv;
      out[rowbase + 32 + ln] = accO1[0] + boutv;
    }
  }
}

extern "C" void kernel_launch(void* const* d_in, const int* in_sizes, int n_in,
                              void* d_out, int out_size, void* d_ws, size_t ws_size,
                              hipStream_t stream) {
  (void)n_in; (void)out_size; (void)ws_size;  // needs ~313 KB of ws
  const float* x    = (const float*)d_in[0];
  const float* W0   = (const float*)d_in[1];
  const float* b0   = (const float*)d_in[2];
  const float* Wh   = (const float*)d_in[3];
  const float* bh   = (const float*)d_in[4];
  const float* Wout = (const float*)d_in[5];
  const float* bout = (const float*)d_in[6];
  float* out = (float*)d_out;

  char* ws = (char*)d_ws;
  _Float16* wfrag   = (_Float16*)(ws);
  _Float16* w0frag  = (_Float16*)(ws + 294912);
  float*    biasC   = (float*)(ws + 299008);
  _Float16* woutf16 = (_Float16*)(ws + 304128);

  const int n = in_sizes[0] / 4;  // 1048576 points

  prep_kernel<<<dim3(160), dim3(256), 0, stream>>>(W0, b0, Wh, bh, Wout,
                                                   wfrag, w0frag, biasC, woutf16);
  mlp_fused<<<dim3(n / 256), dim3(256), 0, stream>>>(x, wfrag, w0frag, biasC,
                                                     woutf16, bout, out);
}